// Round 2
// baseline (93.966 us; speedup 1.0000x reference)
//
#include <hip/hip_runtime.h>

#define T_TRIG 48
#define S_SPAN 128
#define NN (T_TRIG * S_SPAN)      // 6144 nodes
#define D 128                     // feature dim (= HEADS*HEAD_DIM = in dim)

// ---------------------------------------------------------------------------
// GEMM  H = X @ W  (NNxD @ DxD), fused epilogue computing per-node attention
// scalars. No LDS: W rows served from L1/L2 (broadcast-friendly), X from L2.
// Block: 256 threads = 16 tx (8 cols) x 16 ty (2 rows). Tile 32x128.
// ---------------------------------------------------------------------------
__global__ __launch_bounds__(256) void gemm_att_kernel(
    const float* __restrict__ X, const float* __restrict__ W,
    const float* __restrict__ att_s, const float* __restrict__ att_d,
    float* __restrict__ H, float* __restrict__ asrc, float* __restrict__ adst)
{
    const int tid = threadIdx.x;
    const int tx = tid & 15;
    const int ty = tid >> 4;
    const int i0 = blockIdx.x * 32 + ty * 2;
    const int j0 = tx * 8;

    float acc[2][8];
    #pragma unroll
    for (int a = 0; a < 2; ++a)
        #pragma unroll
        for (int b = 0; b < 8; ++b) acc[a][b] = 0.f;

    const float* x0 = X + (size_t)i0 * D;
    #pragma unroll 4
    for (int k = 0; k < D; k += 4) {
        float4 xa4 = *(const float4*)(x0 + k);
        float4 xb4 = *(const float4*)(x0 + D + k);
        float xa[4] = {xa4.x, xa4.y, xa4.z, xa4.w};
        float xb[4] = {xb4.x, xb4.y, xb4.z, xb4.w};
        #pragma unroll
        for (int kk = 0; kk < 4; ++kk) {
            const float* wr = W + (k + kk) * D + j0;
            float4 w0 = *(const float4*)(wr);
            float4 w1 = *(const float4*)(wr + 4);
            float wv[8] = {w0.x, w0.y, w0.z, w0.w, w1.x, w1.y, w1.z, w1.w};
            #pragma unroll
            for (int jj = 0; jj < 8; ++jj) {
                acc[0][jj] = fmaf(xa[kk], wv[jj], acc[0][jj]);
                acc[1][jj] = fmaf(xb[kk], wv[jj], acc[1][jj]);
            }
        }
    }

    #pragma unroll
    for (int ii = 0; ii < 2; ++ii) {
        float4 o0 = {acc[ii][0], acc[ii][1], acc[ii][2], acc[ii][3]};
        float4 o1 = {acc[ii][4], acc[ii][5], acc[ii][6], acc[ii][7]};
        *(float4*)&H[(size_t)(i0 + ii) * D + j0]     = o0;
        *(float4*)&H[(size_t)(i0 + ii) * D + j0 + 4] = o1;
    }

    // attention scalars: head = j0/32; reduce over the 4 tx-lanes of one head
    const int head = tx >> 2;
    const int dbase = head * 32 + (tx & 3) * 8;
    float asv[8], adv[8];
    #pragma unroll
    for (int jj = 0; jj < 8; ++jj) {
        asv[jj] = att_s[dbase + jj];
        adv[jj] = att_d[dbase + jj];
    }
    #pragma unroll
    for (int ii = 0; ii < 2; ++ii) {
        float ps = 0.f, pd = 0.f;
        #pragma unroll
        for (int jj = 0; jj < 8; ++jj) {
            ps = fmaf(acc[ii][jj], asv[jj], ps);
            pd = fmaf(acc[ii][jj], adv[jj], pd);
        }
        ps += __shfl_xor(ps, 1); ps += __shfl_xor(ps, 2);
        pd += __shfl_xor(pd, 1); pd += __shfl_xor(pd, 2);
        if ((tx & 3) == 0) {
            asrc[(i0 + ii) * 4 + head] = ps;
            adst[(i0 + ii) * 4 + head] = pd;
        }
    }
}

// ---------------------------------------------------------------------------
// Row aggregation: block per (row r, head h) = 192 blocks, 256 threads.
// Stages H[r,:,h*32:h*32+32] (16 KB) + asrc row slice, then rank-1 updates:
// num[c,f] = sum_{c'} exp(lrelu(asrc[c']+adst[c])) * H[c',f]   (no max shift)
// Writes num_row (per-dest unnormalized numerators) and den_row.
// ---------------------------------------------------------------------------
__global__ __launch_bounds__(256) void row_agg_kernel(
    const float* __restrict__ H, const float* __restrict__ asrc,
    const float* __restrict__ adst, float* __restrict__ num_row,
    float* __restrict__ den_row)
{
    __shared__ float sh_h[S_SPAN][32];
    __shared__ float sh_as[S_SPAN];
    const int tid = threadIdx.x;
    const int r = blockIdx.x >> 2;
    const int h = blockIdx.x & 3;
    const int base = r * S_SPAN;

    #pragma unroll
    for (int it = 0; it < 4; ++it) {
        int chunk = tid + it * 256;          // 1024 float4 chunks
        int cp = chunk >> 3, fc = chunk & 7;
        *(float4*)&sh_h[cp][fc * 4] =
            *(const float4*)&H[(size_t)(base + cp) * D + h * 32 + fc * 4];
    }
    if (tid < S_SPAN) sh_as[tid] = asrc[(base + tid) * 4 + h];
    __syncthreads();

    const int fg = tid & 3;      // f8 group: features fg*8 .. fg*8+7
    const int cth = tid >> 2;    // 0..63 ; dests c = cth, cth+64
    const float ad0 = adst[(base + cth) * 4 + h];
    const float ad1 = adst[(base + cth + 64) * 4 + h];
    float4 n00 = {0,0,0,0}, n01 = {0,0,0,0}, n10 = {0,0,0,0}, n11 = {0,0,0,0};
    float den0 = 0.f, den1 = 0.f;

    #pragma unroll 2
    for (int cp = 0; cp < S_SPAN; ++cp) {
        float a = sh_as[cp];
        float4 h0 = *(float4*)&sh_h[cp][fg * 8];
        float4 h1 = *(float4*)&sh_h[cp][fg * 8 + 4];
        float e0 = a + ad0; e0 = fmaxf(e0, 0.2f * e0);
        float e1 = a + ad1; e1 = fmaxf(e1, 0.2f * e1);
        float w0 = __expf(e0);
        float w1 = __expf(e1);
        den0 += w0; den1 += w1;
        n00.x = fmaf(w0, h0.x, n00.x); n00.y = fmaf(w0, h0.y, n00.y);
        n00.z = fmaf(w0, h0.z, n00.z); n00.w = fmaf(w0, h0.w, n00.w);
        n01.x = fmaf(w0, h1.x, n01.x); n01.y = fmaf(w0, h1.y, n01.y);
        n01.z = fmaf(w0, h1.z, n01.z); n01.w = fmaf(w0, h1.w, n01.w);
        n10.x = fmaf(w1, h0.x, n10.x); n10.y = fmaf(w1, h0.y, n10.y);
        n10.z = fmaf(w1, h0.z, n10.z); n10.w = fmaf(w1, h0.w, n10.w);
        n11.x = fmaf(w1, h1.x, n11.x); n11.y = fmaf(w1, h1.y, n11.y);
        n11.z = fmaf(w1, h1.z, n11.z); n11.w = fmaf(w1, h1.w, n11.w);
    }

    const int n0 = base + cth, n1 = n0 + 64;
    *(float4*)&num_row[(size_t)n0 * D + h * 32 + fg * 8]     = n00;
    *(float4*)&num_row[(size_t)n0 * D + h * 32 + fg * 8 + 4] = n01;
    *(float4*)&num_row[(size_t)n1 * D + h * 32 + fg * 8]     = n10;
    *(float4*)&num_row[(size_t)n1 * D + h * 32 + fg * 8 + 4] = n11;
    if (fg == 0) {
        den_row[n0 * 4 + h] = den0;
        den_row[n1 * 4 + h] = den1;
    }
}

// ---------------------------------------------------------------------------
// Column aggregation + finalize: block per column c = 128 blocks, 256 threads.
// Stages H[:,c,:] (48x128 = 24 KB). Adds col-part (excluding own row), merges
// with row-part, normalizes, + bias, ELU.
// ---------------------------------------------------------------------------
__global__ __launch_bounds__(256) void col_agg_kernel(
    const float* __restrict__ H, const float* __restrict__ asrc,
    const float* __restrict__ adst, const float* __restrict__ num_row,
    const float* __restrict__ den_row, const float* __restrict__ bias,
    float* __restrict__ out)
{
    __shared__ float sh_h[T_TRIG][D];     // 24 KB
    __shared__ float sh_as[4][T_TRIG];
    const int c = blockIdx.x;
    const int tid = threadIdx.x;

    #pragma unroll
    for (int it = 0; it < 6; ++it) {
        int chunk = tid + it * 256;        // 1536 float4 chunks
        int t = chunk >> 5, fc = chunk & 31;
        *(float4*)&sh_h[t][fc * 4] =
            *(const float4*)&H[(size_t)(t * S_SPAN + c) * D + fc * 4];
    }
    if (tid < 4 * T_TRIG) {
        int hh = tid / T_TRIG, t = tid - hh * T_TRIG;
        sh_as[hh][t] = asrc[(t * S_SPAN + c) * 4 + hh];
    }
    __syncthreads();

    const int f4g = tid & 31;    // feature float4 index: f = f4g*4
    const int tg = tid >> 5;     // 0..7 ; dests t = tg*6 .. tg*6+5
    const int head = f4g >> 3;

    float4 num[6];
    float den[6], ad[6];
    #pragma unroll
    for (int dd = 0; dd < 6; ++dd) {
        num[dd] = {0,0,0,0};
        den[dd] = 0.f;
        ad[dd] = adst[((tg * 6 + dd) * S_SPAN + c) * 4 + head];
    }

    for (int tp = 0; tp < T_TRIG; ++tp) {
        float a = sh_as[head][tp];
        float4 hv = *(float4*)&sh_h[tp][f4g * 4];
        #pragma unroll
        for (int dd = 0; dd < 6; ++dd) {
            float e = a + ad[dd];
            e = fmaxf(e, 0.2f * e);
            float w = __expf(e);
            w = (tp == tg * 6 + dd) ? 0.f : w;   // exclude own row
            den[dd] += w;
            num[dd].x = fmaf(w, hv.x, num[dd].x);
            num[dd].y = fmaf(w, hv.y, num[dd].y);
            num[dd].z = fmaf(w, hv.z, num[dd].z);
            num[dd].w = fmaf(w, hv.w, num[dd].w);
        }
    }

    const float4 b4 = *(const float4*)&bias[f4g * 4];
    #pragma unroll
    for (int dd = 0; dd < 6; ++dd) {
        int n = (tg * 6 + dd) * S_SPAN + c;
        float4 nr = *(const float4*)&num_row[(size_t)n * D + f4g * 4];
        float dr = den_row[n * 4 + head];
        float inv = 1.f / (dr + den[dd]);
        float4 o;
        o.x = (nr.x + num[dd].x) * inv + b4.x;
        o.y = (nr.y + num[dd].y) * inv + b4.y;
        o.z = (nr.z + num[dd].z) * inv + b4.z;
        o.w = (nr.w + num[dd].w) * inv + b4.w;
        o.x = o.x > 0.f ? o.x : (__expf(o.x) - 1.f);
        o.y = o.y > 0.f ? o.y : (__expf(o.y) - 1.f);
        o.z = o.z > 0.f ? o.z : (__expf(o.z) - 1.f);
        o.w = o.w > 0.f ? o.w : (__expf(o.w) - 1.f);
        *(float4*)&out[(size_t)n * D + f4g * 4] = o;
    }
}

// ---------------------------------------------------------------------------
extern "C" void kernel_launch(void* const* d_in, const int* in_sizes, int n_in,
                              void* d_out, int out_size, void* d_ws, size_t ws_size,
                              hipStream_t stream)
{
    const float* pe  = (const float*)d_in[0];
    const float* W1  = (const float*)d_in[1];
    const float* as1 = (const float*)d_in[2];
    const float* ad1 = (const float*)d_in[3];
    const float* b1  = (const float*)d_in[4];
    const float* W2  = (const float*)d_in[5];
    const float* as2 = (const float*)d_in[6];
    const float* ad2 = (const float*)d_in[7];
    const float* b2  = (const float*)d_in[8];
    float* out = (float*)d_out;

    float* ws = (float*)d_ws;
    float* H     = ws;                       // NN*D
    float* X2    = H + (size_t)NN * D;       // NN*D
    float* numr  = X2 + (size_t)NN * D;      // NN*D
    float* asrcb = numr + (size_t)NN * D;    // NN*4
    float* adstb = asrcb + (size_t)NN * 4;   // NN*4
    float* denb  = adstb + (size_t)NN * 4;   // NN*4

    // layer 1
    gemm_att_kernel<<<dim3(NN / 32), dim3(256), 0, stream>>>(pe, W1, as1, ad1, H, asrcb, adstb);
    row_agg_kernel<<<dim3(T_TRIG * 4), dim3(256), 0, stream>>>(H, asrcb, adstb, numr, denb);
    col_agg_kernel<<<dim3(S_SPAN), dim3(256), 0, stream>>>(H, asrcb, adstb, numr, denb, b1, X2);
    // layer 2
    gemm_att_kernel<<<dim3(NN / 32), dim3(256), 0, stream>>>(X2, W2, as2, ad2, H, asrcb, adstb);
    row_agg_kernel<<<dim3(T_TRIG * 4), dim3(256), 0, stream>>>(H, asrcb, adstb, numr, denb);
    col_agg_kernel<<<dim3(S_SPAN), dim3(256), 0, stream>>>(H, asrcb, adstb, numr, denb, b2, out);
}

// Round 3
// 78.419 us; speedup vs baseline: 1.1983x; 1.1983x over previous
//
#include <hip/hip_runtime.h>

#define T_TRIG 48
#define S_SPAN 128
#define NN (T_TRIG * S_SPAN)      // 6144 nodes
#define D 128                     // feature dim (= HEADS*HEAD_DIM = in dim)

typedef __attribute__((ext_vector_type(8))) short sh8;
typedef __attribute__((ext_vector_type(4))) float f32x4;

__device__ inline unsigned short f2bf(float v) {
    unsigned u = __float_as_uint(v);
    unsigned r = u + 0x7FFFu + ((u >> 16) & 1u);   // round-to-nearest-even
    return (unsigned short)(r >> 16);
}
__device__ inline float bf2f(unsigned short b) {
    return __uint_as_float(((unsigned)b) << 16);
}

// ---------------------------------------------------------------------------
// Pack W (fp32 [128][128]) into MFMA B-fragment-ready hi/lo bf16 buffers.
// Layout: frag[(ntile*4 + kchunk)*64 + lane] = 8 bf16 with
//   k = kchunk*32 + (lane>>4)*8 + i,  n = ntile*16 + (lane&15).
// 16 blocks x 64 threads: blocks 0-7 pack W1 ntile b, 8-15 pack W2 ntile b-8.
// ---------------------------------------------------------------------------
__global__ __launch_bounds__(64) void pack_w_kernel(
    const float* __restrict__ W1, const float* __restrict__ W2,
    unsigned short* __restrict__ w1h, unsigned short* __restrict__ w1l,
    unsigned short* __restrict__ w2h, unsigned short* __restrict__ w2l)
{
    const int b = blockIdx.x;
    const int l = threadIdx.x;
    const float* W = (b < 8) ? W1 : W2;
    unsigned short* wh = (b < 8) ? w1h : w2h;
    unsigned short* wl = (b < 8) ? w1l : w2l;
    const int nt = b & 7;
    const int n = nt * 16 + (l & 15);
    const int kgb = (l >> 4) * 8;

    #pragma unroll
    for (int kc = 0; kc < 4; ++kc) {
        unsigned short hb[8], lb[8];
        #pragma unroll
        for (int i = 0; i < 8; ++i) {
            int k = kc * 32 + kgb + i;
            float v = W[k * D + n];
            unsigned short h = f2bf(v);
            hb[i] = h;
            lb[i] = f2bf(v - bf2f(h));
        }
        size_t base = ((size_t)(nt * 4 + kc) * 64 + l) * 8;
        #pragma unroll
        for (int i = 0; i < 8; ++i) { wh[base + i] = hb[i]; wl[base + i] = lb[i]; }
    }
}

// ---------------------------------------------------------------------------
// MFMA GEMM  H = X @ W  with split-bf16 (3 MFMAs per tile-chunk), fused
// attention-scalar epilogue. 768 blocks x 64 threads (1 wave).
// Block = (mtile mt = bid>>1 : rows mt*16..+15) x (nhalf nh = bid&1 : cols nh*64..+63).
// ---------------------------------------------------------------------------
__global__ __launch_bounds__(64) void gemm_mfma_kernel(
    const float* __restrict__ X,
    const unsigned short* __restrict__ Wh, const unsigned short* __restrict__ Wl,
    const float* __restrict__ att_s, const float* __restrict__ att_d,
    float* __restrict__ H, float* __restrict__ asrc, float* __restrict__ adst)
{
    const int l = threadIdx.x;
    const int mt = blockIdx.x >> 1;
    const int nh = blockIdx.x & 1;
    const int c = l & 15;       // A row / D col / B col (per fragment role)
    const int kg = l >> 4;      // k-group
    const int row0 = mt * 16;

    const sh8* Wh8 = (const sh8*)Wh;
    const sh8* Wl8 = (const sh8*)Wl;

    f32x4 acc[4] = {f32x4{0,0,0,0}, f32x4{0,0,0,0}, f32x4{0,0,0,0}, f32x4{0,0,0,0}};

    #pragma unroll
    for (int kc = 0; kc < 4; ++kc) {
        const float* xp = X + (size_t)(row0 + c) * D + kc * 32 + kg * 8;
        float4 x0 = *(const float4*)xp;
        float4 x1 = *(const float4*)(xp + 4);
        float xs[8] = {x0.x, x0.y, x0.z, x0.w, x1.x, x1.y, x1.z, x1.w};
        sh8 ah, al;
        #pragma unroll
        for (int i = 0; i < 8; ++i) {
            unsigned short h = f2bf(xs[i]);
            ah[i] = (short)h;
            al[i] = (short)f2bf(xs[i] - bf2f(h));
        }
        #pragma unroll
        for (int ntl = 0; ntl < 4; ++ntl) {
            int ntg = nh * 4 + ntl;
            sh8 bh = Wh8[(ntg * 4 + kc) * 64 + l];
            sh8 bl = Wl8[(ntg * 4 + kc) * 64 + l];
            acc[ntl] = __builtin_amdgcn_mfma_f32_16x16x32_bf16(ah, bh, acc[ntl], 0, 0, 0);
            acc[ntl] = __builtin_amdgcn_mfma_f32_16x16x32_bf16(al, bh, acc[ntl], 0, 0, 0);
            acc[ntl] = __builtin_amdgcn_mfma_f32_16x16x32_bf16(ah, bl, acc[ntl], 0, 0, 0);
        }
    }

    // store H: D layout col=l&15, row=(l>>4)*4+i
    #pragma unroll
    for (int ntl = 0; ntl < 4; ++ntl) {
        #pragma unroll
        for (int i = 0; i < 4; ++i) {
            H[(size_t)(row0 + kg * 4 + i) * D + nh * 64 + ntl * 16 + c] = acc[ntl][i];
        }
    }

    // attention scalars: this block covers heads nh*2, nh*2+1 completely.
    float asv[4], adv[4];
    #pragma unroll
    for (int ntl = 0; ntl < 4; ++ntl) {
        int d = (nh * 2 + (ntl >> 1)) * 32 + (ntl & 1) * 16 + c;
        asv[ntl] = att_s[d];
        adv[ntl] = att_d[d];
    }
    #pragma unroll
    for (int i = 0; i < 4; ++i) {
        float ps0 = acc[0][i] * asv[0] + acc[1][i] * asv[1];
        float ps1 = acc[2][i] * asv[2] + acc[3][i] * asv[3];
        float pd0 = acc[0][i] * adv[0] + acc[1][i] * adv[1];
        float pd1 = acc[2][i] * adv[2] + acc[3][i] * adv[3];
        #pragma unroll
        for (int o = 1; o < 16; o <<= 1) {
            ps0 += __shfl_xor(ps0, o); ps1 += __shfl_xor(ps1, o);
            pd0 += __shfl_xor(pd0, o); pd1 += __shfl_xor(pd1, o);
        }
        if (c == 0) {
            int rr = row0 + kg * 4 + i;
            asrc[rr * 4 + nh * 2 + 0] = ps0;
            asrc[rr * 4 + nh * 2 + 1] = ps1;
            adst[rr * 4 + nh * 2 + 0] = pd0;
            adst[rr * 4 + nh * 2 + 1] = pd1;
        }
    }
}

// ---------------------------------------------------------------------------
// Row aggregation: block per (row r, head h) = 192 blocks, 256 threads.
// num[c,f] = sum_{c'} exp(lrelu(asrc[c']+adst[c])) * H[c',f]   (no max shift)
// ---------------------------------------------------------------------------
__global__ __launch_bounds__(256) void row_agg_kernel(
    const float* __restrict__ H, const float* __restrict__ asrc,
    const float* __restrict__ adst, float* __restrict__ num_row,
    float* __restrict__ den_row)
{
    __shared__ float sh_h[S_SPAN][32];
    __shared__ float sh_as[S_SPAN];
    const int tid = threadIdx.x;
    const int r = blockIdx.x >> 2;
    const int h = blockIdx.x & 3;
    const int base = r * S_SPAN;

    #pragma unroll
    for (int it = 0; it < 4; ++it) {
        int chunk = tid + it * 256;
        int cp = chunk >> 3, fc = chunk & 7;
        *(float4*)&sh_h[cp][fc * 4] =
            *(const float4*)&H[(size_t)(base + cp) * D + h * 32 + fc * 4];
    }
    if (tid < S_SPAN) sh_as[tid] = asrc[(base + tid) * 4 + h];
    __syncthreads();

    const int fg = tid & 3;
    const int cth = tid >> 2;
    const float ad0 = adst[(base + cth) * 4 + h];
    const float ad1 = adst[(base + cth + 64) * 4 + h];
    float4 n00 = {0,0,0,0}, n01 = {0,0,0,0}, n10 = {0,0,0,0}, n11 = {0,0,0,0};
    float den0 = 0.f, den1 = 0.f;

    #pragma unroll 2
    for (int cp = 0; cp < S_SPAN; ++cp) {
        float a = sh_as[cp];
        float4 h0 = *(float4*)&sh_h[cp][fg * 8];
        float4 h1 = *(float4*)&sh_h[cp][fg * 8 + 4];
        float e0 = a + ad0; e0 = fmaxf(e0, 0.2f * e0);
        float e1 = a + ad1; e1 = fmaxf(e1, 0.2f * e1);
        float w0 = __expf(e0);
        float w1 = __expf(e1);
        den0 += w0; den1 += w1;
        n00.x = fmaf(w0, h0.x, n00.x); n00.y = fmaf(w0, h0.y, n00.y);
        n00.z = fmaf(w0, h0.z, n00.z); n00.w = fmaf(w0, h0.w, n00.w);
        n01.x = fmaf(w0, h1.x, n01.x); n01.y = fmaf(w0, h1.y, n01.y);
        n01.z = fmaf(w0, h1.z, n01.z); n01.w = fmaf(w0, h1.w, n01.w);
        n10.x = fmaf(w1, h0.x, n10.x); n10.y = fmaf(w1, h0.y, n10.y);
        n10.z = fmaf(w1, h0.z, n10.z); n10.w = fmaf(w1, h0.w, n10.w);
        n11.x = fmaf(w1, h1.x, n11.x); n11.y = fmaf(w1, h1.y, n11.y);
        n11.z = fmaf(w1, h1.z, n11.z); n11.w = fmaf(w1, h1.w, n11.w);
    }

    const int n0 = base + cth, n1 = n0 + 64;
    *(float4*)&num_row[(size_t)n0 * D + h * 32 + fg * 8]     = n00;
    *(float4*)&num_row[(size_t)n0 * D + h * 32 + fg * 8 + 4] = n01;
    *(float4*)&num_row[(size_t)n1 * D + h * 32 + fg * 8]     = n10;
    *(float4*)&num_row[(size_t)n1 * D + h * 32 + fg * 8 + 4] = n11;
    if (fg == 0) {
        den_row[n0 * 4 + h] = den0;
        den_row[n1 * 4 + h] = den1;
    }
}

// ---------------------------------------------------------------------------
// Column aggregation + finalize: block per column c = 128 blocks, 256 threads.
// ---------------------------------------------------------------------------
__global__ __launch_bounds__(256) void col_agg_kernel(
    const float* __restrict__ H, const float* __restrict__ asrc,
    const float* __restrict__ adst, const float* __restrict__ num_row,
    const float* __restrict__ den_row, const float* __restrict__ bias,
    float* __restrict__ out)
{
    __shared__ float sh_h[T_TRIG][D];
    __shared__ float sh_as[4][T_TRIG];
    const int c = blockIdx.x;
    const int tid = threadIdx.x;

    #pragma unroll
    for (int it = 0; it < 6; ++it) {
        int chunk = tid + it * 256;
        int t = chunk >> 5, fc = chunk & 31;
        *(float4*)&sh_h[t][fc * 4] =
            *(const float4*)&H[(size_t)(t * S_SPAN + c) * D + fc * 4];
    }
    if (tid < 4 * T_TRIG) {
        int hh = tid / T_TRIG, t = tid - hh * T_TRIG;
        sh_as[hh][t] = asrc[(t * S_SPAN + c) * 4 + hh];
    }
    __syncthreads();

    const int f4g = tid & 31;
    const int tg = tid >> 5;
    const int head = f4g >> 3;

    float4 num[6];
    float den[6], ad[6];
    #pragma unroll
    for (int dd = 0; dd < 6; ++dd) {
        num[dd] = {0,0,0,0};
        den[dd] = 0.f;
        ad[dd] = adst[((tg * 6 + dd) * S_SPAN + c) * 4 + head];
    }

    for (int tp = 0; tp < T_TRIG; ++tp) {
        float a = sh_as[head][tp];
        float4 hv = *(float4*)&sh_h[tp][f4g * 4];
        #pragma unroll
        for (int dd = 0; dd < 6; ++dd) {
            float e = a + ad[dd];
            e = fmaxf(e, 0.2f * e);
            float w = __expf(e);
            w = (tp == tg * 6 + dd) ? 0.f : w;
            den[dd] += w;
            num[dd].x = fmaf(w, hv.x, num[dd].x);
            num[dd].y = fmaf(w, hv.y, num[dd].y);
            num[dd].z = fmaf(w, hv.z, num[dd].z);
            num[dd].w = fmaf(w, hv.w, num[dd].w);
        }
    }

    const float4 b4 = *(const float4*)&bias[f4g * 4];
    #pragma unroll
    for (int dd = 0; dd < 6; ++dd) {
        int n = (tg * 6 + dd) * S_SPAN + c;
        float4 nr = *(const float4*)&num_row[(size_t)n * D + f4g * 4];
        float dr = den_row[n * 4 + head];
        float inv = 1.f / (dr + den[dd]);
        float4 o;
        o.x = (nr.x + num[dd].x) * inv + b4.x;
        o.y = (nr.y + num[dd].y) * inv + b4.y;
        o.z = (nr.z + num[dd].z) * inv + b4.z;
        o.w = (nr.w + num[dd].w) * inv + b4.w;
        o.x = o.x > 0.f ? o.x : (__expf(o.x) - 1.f);
        o.y = o.y > 0.f ? o.y : (__expf(o.y) - 1.f);
        o.z = o.z > 0.f ? o.z : (__expf(o.z) - 1.f);
        o.w = o.w > 0.f ? o.w : (__expf(o.w) - 1.f);
        *(float4*)&out[(size_t)n * D + f4g * 4] = o;
    }
}

// ---------------------------------------------------------------------------
extern "C" void kernel_launch(void* const* d_in, const int* in_sizes, int n_in,
                              void* d_out, int out_size, void* d_ws, size_t ws_size,
                              hipStream_t stream)
{
    const float* pe  = (const float*)d_in[0];
    const float* W1  = (const float*)d_in[1];
    const float* as1 = (const float*)d_in[2];
    const float* ad1 = (const float*)d_in[3];
    const float* b1  = (const float*)d_in[4];
    const float* W2  = (const float*)d_in[5];
    const float* as2 = (const float*)d_in[6];
    const float* ad2 = (const float*)d_in[7];
    const float* b2  = (const float*)d_in[8];
    float* out = (float*)d_out;

    char* ws = (char*)d_ws;
    float* H     = (float*)ws;                                   // NN*D f32
    float* X2    = H + (size_t)NN * D;                           // NN*D f32
    float* numr  = X2 + (size_t)NN * D;                          // NN*D f32
    float* asrcb = numr + (size_t)NN * D;                        // NN*4
    float* adstb = asrcb + (size_t)NN * 4;                       // NN*4
    float* denb  = adstb + (size_t)NN * 4;                       // NN*4
    unsigned short* w1h = (unsigned short*)(denb + (size_t)NN * 4);
    unsigned short* w1l = w1h + 128 * 128;
    unsigned short* w2h = w1l + 128 * 128;
    unsigned short* w2l = w2h + 128 * 128;

    pack_w_kernel<<<dim3(16), dim3(64), 0, stream>>>(W1, W2, w1h, w1l, w2h, w2l);

    // layer 1
    gemm_mfma_kernel<<<dim3(768), dim3(64), 0, stream>>>(pe, w1h, w1l, as1, ad1, H, asrcb, adstb);
    row_agg_kernel<<<dim3(T_TRIG * 4), dim3(256), 0, stream>>>(H, asrcb, adstb, numr, denb);
    col_agg_kernel<<<dim3(S_SPAN), dim3(256), 0, stream>>>(H, asrcb, adstb, numr, denb, b1, X2);
    // layer 2
    gemm_mfma_kernel<<<dim3(768), dim3(64), 0, stream>>>(X2, w2h, w2l, as2, ad2, H, asrcb, adstb);
    row_agg_kernel<<<dim3(T_TRIG * 4), dim3(256), 0, stream>>>(H, asrcb, adstb, numr, denb);
    col_agg_kernel<<<dim3(S_SPAN), dim3(256), 0, stream>>>(H, asrcb, adstb, numr, denb, b2, out);
}